// Round 1
// baseline (10866.368 us; speedup 1.0000x reference)
//
#include <hip/hip_runtime.h>
#include <hip/hip_bf16.h>

// ============================================================================
// WindowAttention round 4: occupancy restructure.
// rocprof r3: VALUBusy 16.6%, Occupancy 12.26% (= 1 wave/SIMD), HBM 0.3%,
// MFMA 0 -> pure latency-bound. Fix: 512 threads/block (4 threads/token),
// halving per-thread work and doubling waves/SIMD to 2. Same f32 math.
//  - qkv dim split {0-7, 8-15, 16-23, 22-29} (dims 22,23 computed twice,
//    bitwise-identical -> benign LDS write race; keeps all reg indices
//    compile-time, no divergent guards).
//  - attention key-range split 4-way, 4-lane butterfly online-softmax merge.
//  - projection: 1 token x 45 outputs/thread (acc regs 90 -> 45).
//  - k/v LDS rows skewed by (r>>4)*4 floats: breaks 4-way same-bank aliasing
//    of the 4 per-wave key-row streams (32*36 = 0 mod 32 banks).
// LDS 147,200 B -> still 1 block/CU, but 8 waves = 2/SIMD.
// ============================================================================

typedef unsigned short u16;
typedef unsigned int   u32;

#define NTOK 128
#define CDIM 180
#define NHEAD 6
#define XSTR 182            // f32 x stride
#define KVSTR 36            // f32 k/v row stride (before skew)
#define KVSZ  4640          // 127*36 + 28 + 32, rounded up
#define SLSTR 33            // f32 slab stride
#define QKSCALE 0.18257418583505536f   // 30^-0.5

__device__ __forceinline__ float bflo(u32 u){ return __uint_as_float(u << 16); }
__device__ __forceinline__ float bfhi(u32 u){ return __uint_as_float(u & 0xFFFF0000u); }
__device__ __forceinline__ float bf2f(u16 v){ return __uint_as_float(((u32)v) << 16); }

// skewed k/v row start: rows r, r+16, r+32, r+48... land on distinct banks
__device__ __forceinline__ int kvrow(int r){ return r * KVSTR + ((r >> 4) << 2); }

template<bool F32> __device__ __forceinline__ float ld1(const void* p, size_t i) {
  if constexpr (F32) return reinterpret_cast<const float*>(p)[i];
  else               return bf2f(reinterpret_cast<const u16*>(p)[i]);
}
template<bool F32> __device__ __forceinline__ float2 ld2(const void* p, size_t i) {
  if constexpr (F32) return *reinterpret_cast<const float2*>(reinterpret_cast<const float*>(p) + i);
  else {
    u32 r = *reinterpret_cast<const u32*>(reinterpret_cast<const u16*>(p) + i);
    return float2{bflo(r), bfhi(r)};
  }
}
template<bool F32> __device__ __forceinline__ float4 ld4(const void* p, size_t i) {
  if constexpr (F32) return *reinterpret_cast<const float4*>(reinterpret_cast<const float*>(p) + i);
  else {
    uint2 r = *reinterpret_cast<const uint2*>(reinterpret_cast<const u16*>(p) + i);
    return float4{bflo(r.x), bfhi(r.x), bflo(r.y), bfhi(r.y)};
  }
}

// ---------------------------------------------------------------------------
// dtype detector (unchanged from round 3): flag=1 => bf16 inputs.
// ---------------------------------------------------------------------------
__global__ void detect_dtype(const u32* __restrict__ xw, int* __restrict__ flag) {
  __shared__ int cnt[256];
  int c = 0;
  for (int i = threadIdx.x; i < 4096; i += 256) {
    u32 e = (xw[i] >> 7) & 0xFF;
    c += (e >= 0x58 && e <= 0x90) ? 1 : 0;
  }
  cnt[threadIdx.x] = c;
  __syncthreads();
  if (threadIdx.x == 0) {
    int t = 0;
    for (int i = 0; i < 256; ++i) t += cnt[i];
    flag[0] = (t >= 2458) ? 1 : 0;
  }
}

// ---------------------------------------------------------------------------
// fused per-window body, 512 threads = 128 tokens x 4 lanes
// ---------------------------------------------------------------------------
template<bool F32>
__device__ void body(const void* __restrict__ x,    // (1024,128,180)
                     const void* __restrict__ mask, // (64,128,128)
                     const void* __restrict__ rpb,  // (675,6)
                     const void* __restrict__ Wqs,  // (540,180)
                     const void* __restrict__ Wqm,  // (540,180)
                     const void* __restrict__ Wp,   // (180,360)
                     const void* __restrict__ bp,   // (180)
                     float* __restrict__ out,       // (1024,128,180) f32
                     float* x_s, float* k_s, float* v_s, float* slab)
{
  const int tid = threadIdx.x;
  const int b   = blockIdx.x;
  const int n   = tid >> 2;        // token (qkv row / attention query)
  const int j   = tid & 3;         // quarter lane within token quad
  const int off = (j < 3) ? j * 8 : 22;   // qkv dim sub-range start (8 dims)
  const int w64 = b & 63;
  const int lq  = (tid & 63) & ~3; // wave-local quad base lane

  // projection ownership: 1 token x 45 out-cols, acc in registers
  const int rp = tid & 127;
  const int og = tid >> 7;         // wave-uniform
  float acc[45];
  #pragma unroll
  for (int o2 = 0; o2 < 45; ++o2) acc[o2] = 0.f;

  // bias i-coords for self attention (query n)
  const int bi_d = n >> 6, bi_h = (n >> 3) & 7, bi_w = n & 7;

  // ---- stage x window into LDS (f32, exact) ----
  {
    const size_t xbase = (size_t)b * (NTOK * CDIM);
    for (int i = tid * 4; i < NTOK * CDIM; i += 2048) {
      float4 f = ld4<F32>(x, xbase + i);
      int r = i / CDIM, c = i - r * CDIM;     // c stays multiple of 4
      float* dst = &x_s[r * XSTR + c];
      dst[0] = f.x; dst[1] = f.y; dst[2] = f.z; dst[3] = f.w;
    }
  }

  for (int pass = 0; pass < 2; ++pass) {
    const bool self = (pass == 0);
    const void* W = self ? Wqs : Wqm;
    if (!self) {
      __syncthreads();
      // x += sine position encoding, computed on the fly (f32, no rounding)
      for (int i = tid; i < NTOK * CDIM; i += 512) {
        int r = i / CDIM, c = i - r * CDIM;
        int n64 = r & 63;
        int t = (c < 90) ? c : (c - 90);
        float e = (c < 90) ? (float)((n64 >> 3) + 1) : (float)((n64 & 7) + 1);
        float embed = e * 0.78539807f;                 // 2*pi / 8.000001
        float expo  = (float)(t & ~1) * (1.0f / 90.0f);
        float arg   = embed * exp2f(-13.2877124f * expo);  // 10000^-expo
        float pbv   = (t & 1) ? cosf(arg) : sinf(arg);
        x_s[r * XSTR + c] += pbv;
      }
    }
    for (int h = 0; h < NHEAD; ++h) {
      __syncthreads();
      // ---------- qkv: thread (n,j) computes dims [off, off+8) ----------
      float qfull[32];
      {
        float aq[8], ak[8], av[8];
        #pragma unroll
        for (int d = 0; d < 8; ++d) { aq[d] = 0.f; ak[d] = 0.f; av[d] = 0.f; }
        const float* xr = &x_s[n * XSTR];
        const size_t wq0 = (size_t)(0 * CDIM + h * 30 + off) * CDIM;
        const size_t wk0 = (size_t)(1 * CDIM + h * 30 + off) * CDIM;
        const size_t wv0 = (size_t)(2 * CDIM + h * 30 + off) * CDIM;
        for (int c = 0; c < CDIM; c += 4) {
          float2 xa = *reinterpret_cast<const float2*>(xr + c);
          float2 xb = *reinterpret_cast<const float2*>(xr + c + 2);
          #pragma unroll
          for (int d = 0; d < 8; ++d) {
            float4 a = ld4<F32>(W, wq0 + (size_t)d * CDIM + c);
            aq[d] = fmaf(xa.x, a.x, fmaf(xa.y, a.y, fmaf(xb.x, a.z, fmaf(xb.y, a.w, aq[d]))));
            float4 bk = ld4<F32>(W, wk0 + (size_t)d * CDIM + c);
            ak[d] = fmaf(xa.x, bk.x, fmaf(xa.y, bk.y, fmaf(xb.x, bk.z, fmaf(xb.y, bk.w, ak[d]))));
            float4 bv = ld4<F32>(W, wv0 + (size_t)d * CDIM + c);
            av[d] = fmaf(xa.x, bv.x, fmaf(xa.y, bv.y, fmaf(xb.x, bv.z, fmaf(xb.y, bv.w, av[d]))));
          }
        }
        float* krow = &k_s[kvrow(n)];
        float* vrow = &v_s[kvrow(n)];
        #pragma unroll
        for (int d = 0; d < 8; ++d) {
          aq[d] *= QKSCALE;
          krow[off + d] = ak[d];   // dims 22,23 written twice with identical
          vrow[off + d] = av[d];   // values (same fmaf chain) -> benign
        }
        if (j == 0) { krow[30] = 0.f; krow[31] = 0.f; }
        // gather full scaled q row from the 4 quad lanes (compile-time regs)
        #pragma unroll
        for (int t = 0; t < 30; ++t) {
          int jo, dl;
          if (t < 8)       { jo = 0; dl = t; }
          else if (t < 16) { jo = 1; dl = t - 8; }
          else if (t < 22) { jo = 2; dl = t - 16; }
          else             { jo = 3; dl = t - 22; }
          qfull[t] = __shfl(aq[dl], lq + jo);
        }
        qfull[30] = 0.f; qfull[31] = 0.f;
      }
      __syncthreads();
      // ---------- attention: query n, key-range split 4 ways by j ----------
      float o[32];
      #pragma unroll
      for (int d = 0; d < 32; ++d) o[d] = 0.f;
      float m = -1e30f, l = 0.f;

      int jbeg, jcount, kbase;
      if (self) { jbeg = j * 32; jcount = 32; kbase = 0; }
      else      { jbeg = j * 16; jcount = 16; kbase = (n < 64) ? 64 : 0; }
      const int il = self ? n : (n & 63);
      const size_t mbase = (size_t)w64 * (NTOK * NTOK) + (size_t)il * NTOK;

      for (int jj = 0; jj < jcount; jj += 4) {
        const int jl = jbeg + jj;
        const int jg = kbase + jl;
        const float* kb = &k_s[kvrow(jg)];   // jg%16 in {0,4,8,12}: same skew
        float s[4];
        #pragma unroll
        for (int u = 0; u < 4; ++u) {
          const float* kr = kb + u * KVSTR;
          float t0 = 0.f, t1 = 0.f, t2 = 0.f, t3 = 0.f;
          #pragma unroll
          for (int kk = 0; kk < 8; ++kk) {
            float4 kv = *reinterpret_cast<const float4*>(kr + 4 * kk);
            t0 = fmaf(qfull[4 * kk],     kv.x, t0);
            t1 = fmaf(qfull[4 * kk + 1], kv.y, t1);
            t2 = fmaf(qfull[4 * kk + 2], kv.z, t2);
            t3 = fmaf(qfull[4 * kk + 3], kv.w, t3);
          }
          float sv = (t0 + t1) + (t2 + t3);
          sv += ld1<F32>(mask, mbase + (size_t)(jl + u));
          if (self) {
            const int jv = jl + u;
            const int dj = jv >> 6, hj = (jv >> 3) & 7, wj = jv & 7;
            const int idx = (bi_d - dj + 1) * 225 + (bi_h - hj + 7) * 15 + (bi_w - wj + 7);
            sv += ld1<F32>(rpb, (size_t)idx * 6 + h);
          }
          s[u] = sv;
        }
        float M = fmaxf(fmaxf(fmaxf(s[0], s[1]), fmaxf(s[2], s[3])), m);
        float corr = __expf(m - M);
        float p0 = __expf(s[0] - M), p1 = __expf(s[1] - M);
        float p2 = __expf(s[2] - M), p3 = __expf(s[3] - M);
        l = l * corr + ((p0 + p1) + (p2 + p3));
        const float* v0 = &v_s[kvrow(jg)];
        const float* v1 = v0 + KVSTR;
        const float* v2 = v1 + KVSTR;
        const float* v3 = v2 + KVSTR;
        #pragma unroll
        for (int kk = 0; kk < 8; ++kk) {
          float4 a0 = *reinterpret_cast<const float4*>(v0 + 4 * kk);
          float4 a1 = *reinterpret_cast<const float4*>(v1 + 4 * kk);
          float4 a2 = *reinterpret_cast<const float4*>(v2 + 4 * kk);
          float4 a3 = *reinterpret_cast<const float4*>(v3 + 4 * kk);
          o[4*kk]   = fmaf(o[4*kk],   corr, fmaf(p0, a0.x, fmaf(p1, a1.x, fmaf(p2, a2.x, p3 * a3.x))));
          o[4*kk+1] = fmaf(o[4*kk+1], corr, fmaf(p0, a0.y, fmaf(p1, a1.y, fmaf(p2, a2.y, p3 * a3.y))));
          o[4*kk+2] = fmaf(o[4*kk+2], corr, fmaf(p0, a0.z, fmaf(p1, a1.z, fmaf(p2, a2.z, p3 * a3.z))));
          o[4*kk+3] = fmaf(o[4*kk+3], corr, fmaf(p0, a0.w, fmaf(p1, a1.w, fmaf(p2, a2.w, p3 * a3.w))));
        }
        m = M;
      }
      // ---------- 4-lane butterfly merge; lane j==0 writes head-slab ----------
      {
        #pragma unroll
        for (int s2 = 1; s2 <= 2; s2 <<= 1) {
          float m2 = __shfl_xor(m, s2);
          float l2 = __shfl_xor(l, s2);
          float M  = fmaxf(m, m2);
          float e1 = __expf(m - M);
          float e2 = __expf(m2 - M);
          l = l * e1 + l2 * e2;
          #pragma unroll
          for (int d = 0; d < 30; ++d) {
            float o2v = __shfl_xor(o[d], s2);
            o[d] = o[d] * e1 + o2v * e2;
          }
          m = M;
        }
        if (j == 0) {
          const int r = self ? n : ((n + 64) & 127);   // mutual swaps halves
          float* srow = &slab[r * SLSTR];
          const float inv = 1.0f / l;
          #pragma unroll
          for (int d = 0; d < 30; ++d) srow[d] = o[d] * inv;
        }
      }
      __syncthreads();
      // ---------- projection accumulate: slab @ Wp[:, cb:cb+30) ----------
      {
        const int cb = self ? (CDIM + h * 30) : (h * 30);
        float s0[30];
        #pragma unroll
        for (int d = 0; d < 30; ++d) s0[d] = slab[rp * SLSTR + d];
        const size_t wrow = (size_t)(og * 45) * 360 + cb;
        #pragma unroll
        for (int o2 = 0; o2 < 45; ++o2) {
          const size_t wr = wrow + (size_t)o2 * 360;
          float t0 = 0.f;
          #pragma unroll
          for (int d = 0; d < 30; d += 2) {
            float2 w2 = ld2<F32>(Wp, wr + d);
            t0 = fmaf(s0[d], w2.x, fmaf(s0[d + 1], w2.y, t0));
          }
          acc[o2] += t0;
        }
      }
    } // heads
  } // passes

  // ---- epilogue: + b_proj, write FLOAT32 ----
  {
    float* o0 = out + ((size_t)b * NTOK + rp) * CDIM + og * 45;
    #pragma unroll
    for (int o2 = 0; o2 < 45; ++o2) {
      float bb = ld1<F32>(bp, og * 45 + o2);
      o0[o2] = acc[o2] + bb;
    }
  }
}

__global__ __launch_bounds__(512, 2) void fused_all(
    const void* __restrict__ x,    const void* __restrict__ mask,
    const void* __restrict__ rpb,  const void* __restrict__ Wqs,
    const void* __restrict__ Wqm,  const void* __restrict__ Wp,
    const void* __restrict__ bp,   const int* __restrict__ flag,
    float* __restrict__ out)
{
  __shared__ __align__(16) float x_s[NTOK * XSTR];    // 93,184 B
  __shared__ __align__(16) float k_s[KVSZ];           // 18,560 B
  __shared__ __align__(16) float v_s[KVSZ];           // 18,560 B
  __shared__ __align__(16) float slab[NTOK * SLSTR];  // 16,896 B -> 147,200 B
  if (flag[0]) body<false>(x, mask, rpb, Wqs, Wqm, Wp, bp, out, x_s, k_s, v_s, slab);
  else         body<true >(x, mask, rpb, Wqs, Wqm, Wp, bp, out, x_s, k_s, v_s, slab);
}

// ---------------------------------------------------------------------------
extern "C" void kernel_launch(void* const* d_in, const int* in_sizes, int n_in,
                              void* d_out, int out_size, void* d_ws, size_t ws_size,
                              hipStream_t stream) {
  int* flag = (int*)d_ws;   // 4 bytes of ws -- the only scratch used
  detect_dtype<<<1, 256, 0, stream>>>((const u32*)d_in[0], flag);
  fused_all<<<1024, 512, 0, stream>>>(d_in[0], d_in[1], d_in[2], d_in[3],
                                      d_in[4], d_in[5], d_in[6], flag,
                                      (float*)d_out);
}

// Round 2
// 9985.349 us; speedup vs baseline: 1.0882x; 1.0882x over previous
//
#include <hip/hip_runtime.h>
#include <hip/hip_bf16.h>

// ============================================================================
// WindowAttention round 5: remove the accidental VGPR cap.
// Round-4 post-mortem: __launch_bounds__(512, 2) caps VGPRs at 128 (2nd arg =
// min waves/EU); rocprof showed VGPR_Count=112 vs a ~170-reg working set
// (qfull[32]+o[32]+acc[45]+aq/ak/av[24]+addressing) -> ~60 regs spilled to
// scratch -> every wave latency-bound on spill traffic. That explains the
// 18% regression despite 2x occupancy and 40x fewer bank conflicts.
// Fix: __launch_bounds__(512) (compiler still must stay <=256 for an 8-wave
// block => 2 waves/SIMD retained, no spills). Body otherwise identical to
// round 4 (which verified: passed, absmax 0.0078125).
// Extra: og (wave-uniform) via readfirstlane so Wp addressing scalarizes.
// ============================================================================

typedef unsigned short u16;
typedef unsigned int   u32;

#define NTOK 128
#define CDIM 180
#define NHEAD 6
#define XSTR 182            // f32 x stride
#define KVSTR 36            // f32 k/v row stride (before skew)
#define KVSZ  4640          // 127*36 + 28 + 32, rounded up
#define SLSTR 33            // f32 slab stride
#define QKSCALE 0.18257418583505536f   // 30^-0.5

__device__ __forceinline__ float bflo(u32 u){ return __uint_as_float(u << 16); }
__device__ __forceinline__ float bfhi(u32 u){ return __uint_as_float(u & 0xFFFF0000u); }
__device__ __forceinline__ float bf2f(u16 v){ return __uint_as_float(((u32)v) << 16); }

// skewed k/v row start: rows r, r+16, r+32, r+48... land on distinct banks
__device__ __forceinline__ int kvrow(int r){ return r * KVSTR + ((r >> 4) << 2); }

template<bool F32> __device__ __forceinline__ float ld1(const void* p, size_t i) {
  if constexpr (F32) return reinterpret_cast<const float*>(p)[i];
  else               return bf2f(reinterpret_cast<const u16*>(p)[i]);
}
template<bool F32> __device__ __forceinline__ float2 ld2(const void* p, size_t i) {
  if constexpr (F32) return *reinterpret_cast<const float2*>(reinterpret_cast<const float*>(p) + i);
  else {
    u32 r = *reinterpret_cast<const u32*>(reinterpret_cast<const u16*>(p) + i);
    return float2{bflo(r), bfhi(r)};
  }
}
template<bool F32> __device__ __forceinline__ float4 ld4(const void* p, size_t i) {
  if constexpr (F32) return *reinterpret_cast<const float4*>(reinterpret_cast<const float*>(p) + i);
  else {
    uint2 r = *reinterpret_cast<const uint2*>(reinterpret_cast<const u16*>(p) + i);
    return float4{bflo(r.x), bfhi(r.x), bflo(r.y), bfhi(r.y)};
  }
}

// ---------------------------------------------------------------------------
// dtype detector (unchanged): flag=1 => bf16 inputs.
// ---------------------------------------------------------------------------
__global__ void detect_dtype(const u32* __restrict__ xw, int* __restrict__ flag) {
  __shared__ int cnt[256];
  int c = 0;
  for (int i = threadIdx.x; i < 4096; i += 256) {
    u32 e = (xw[i] >> 7) & 0xFF;
    c += (e >= 0x58 && e <= 0x90) ? 1 : 0;
  }
  cnt[threadIdx.x] = c;
  __syncthreads();
  if (threadIdx.x == 0) {
    int t = 0;
    for (int i = 0; i < 256; ++i) t += cnt[i];
    flag[0] = (t >= 2458) ? 1 : 0;
  }
}

// ---------------------------------------------------------------------------
// fused per-window body, 512 threads = 128 tokens x 4 lanes
// ---------------------------------------------------------------------------
template<bool F32>
__device__ void body(const void* __restrict__ x,    // (1024,128,180)
                     const void* __restrict__ mask, // (64,128,128)
                     const void* __restrict__ rpb,  // (675,6)
                     const void* __restrict__ Wqs,  // (540,180)
                     const void* __restrict__ Wqm,  // (540,180)
                     const void* __restrict__ Wp,   // (180,360)
                     const void* __restrict__ bp,   // (180)
                     float* __restrict__ out,       // (1024,128,180) f32
                     float* x_s, float* k_s, float* v_s, float* slab)
{
  const int tid = threadIdx.x;
  const int b   = blockIdx.x;
  const int n   = tid >> 2;        // token (qkv row / attention query)
  const int j   = tid & 3;         // quarter lane within token quad
  const int off = (j < 3) ? j * 8 : 22;   // qkv dim sub-range start (8 dims)
  const int w64 = b & 63;
  const int lq  = (tid & 63) & ~3; // wave-local quad base lane

  // projection ownership: 1 token x 45 out-cols, acc in registers
  const int rp = tid & 127;
  // og is wave-uniform (a wave spans 64 consecutive tids): force scalar
  const int og = __builtin_amdgcn_readfirstlane(tid >> 7);
  float acc[45];
  #pragma unroll
  for (int o2 = 0; o2 < 45; ++o2) acc[o2] = 0.f;

  // bias i-coords for self attention (query n)
  const int bi_d = n >> 6, bi_h = (n >> 3) & 7, bi_w = n & 7;

  // ---- stage x window into LDS (f32, exact) ----
  {
    const size_t xbase = (size_t)b * (NTOK * CDIM);
    for (int i = tid * 4; i < NTOK * CDIM; i += 2048) {
      float4 f = ld4<F32>(x, xbase + i);
      int r = i / CDIM, c = i - r * CDIM;     // c stays multiple of 4
      float* dst = &x_s[r * XSTR + c];
      dst[0] = f.x; dst[1] = f.y; dst[2] = f.z; dst[3] = f.w;
    }
  }

  for (int pass = 0; pass < 2; ++pass) {
    const bool self = (pass == 0);
    const void* W = self ? Wqs : Wqm;
    if (!self) {
      __syncthreads();
      // x += sine position encoding, computed on the fly (f32, no rounding)
      for (int i = tid; i < NTOK * CDIM; i += 512) {
        int r = i / CDIM, c = i - r * CDIM;
        int n64 = r & 63;
        int t = (c < 90) ? c : (c - 90);
        float e = (c < 90) ? (float)((n64 >> 3) + 1) : (float)((n64 & 7) + 1);
        float embed = e * 0.78539807f;                 // 2*pi / 8.000001
        float expo  = (float)(t & ~1) * (1.0f / 90.0f);
        float arg   = embed * exp2f(-13.2877124f * expo);  // 10000^-expo
        float pbv   = (t & 1) ? cosf(arg) : sinf(arg);
        x_s[r * XSTR + c] += pbv;
      }
    }
    for (int h = 0; h < NHEAD; ++h) {
      __syncthreads();
      // ---------- qkv: thread (n,j) computes dims [off, off+8) ----------
      float qfull[32];
      {
        float aq[8], ak[8], av[8];
        #pragma unroll
        for (int d = 0; d < 8; ++d) { aq[d] = 0.f; ak[d] = 0.f; av[d] = 0.f; }
        const float* xr = &x_s[n * XSTR];
        const size_t wq0 = (size_t)(0 * CDIM + h * 30 + off) * CDIM;
        const size_t wk0 = (size_t)(1 * CDIM + h * 30 + off) * CDIM;
        const size_t wv0 = (size_t)(2 * CDIM + h * 30 + off) * CDIM;
        for (int c = 0; c < CDIM; c += 4) {
          float2 xa = *reinterpret_cast<const float2*>(xr + c);
          float2 xb = *reinterpret_cast<const float2*>(xr + c + 2);
          #pragma unroll
          for (int d = 0; d < 8; ++d) {
            float4 a = ld4<F32>(W, wq0 + (size_t)d * CDIM + c);
            aq[d] = fmaf(xa.x, a.x, fmaf(xa.y, a.y, fmaf(xb.x, a.z, fmaf(xb.y, a.w, aq[d]))));
            float4 bk = ld4<F32>(W, wk0 + (size_t)d * CDIM + c);
            ak[d] = fmaf(xa.x, bk.x, fmaf(xa.y, bk.y, fmaf(xb.x, bk.z, fmaf(xb.y, bk.w, ak[d]))));
            float4 bv = ld4<F32>(W, wv0 + (size_t)d * CDIM + c);
            av[d] = fmaf(xa.x, bv.x, fmaf(xa.y, bv.y, fmaf(xb.x, bv.z, fmaf(xb.y, bv.w, av[d]))));
          }
        }
        float* krow = &k_s[kvrow(n)];
        float* vrow = &v_s[kvrow(n)];
        #pragma unroll
        for (int d = 0; d < 8; ++d) {
          aq[d] *= QKSCALE;
          krow[off + d] = ak[d];   // dims 22,23 written twice with identical
          vrow[off + d] = av[d];   // values (same fmaf chain) -> benign
        }
        if (j == 0) { krow[30] = 0.f; krow[31] = 0.f; }
        // gather full scaled q row from the 4 quad lanes (compile-time regs)
        #pragma unroll
        for (int t = 0; t < 30; ++t) {
          int jo, dl;
          if (t < 8)       { jo = 0; dl = t; }
          else if (t < 16) { jo = 1; dl = t - 8; }
          else if (t < 22) { jo = 2; dl = t - 16; }
          else             { jo = 3; dl = t - 22; }
          qfull[t] = __shfl(aq[dl], lq + jo);
        }
        qfull[30] = 0.f; qfull[31] = 0.f;
      }
      __syncthreads();
      // ---------- attention: query n, key-range split 4 ways by j ----------
      float o[32];
      #pragma unroll
      for (int d = 0; d < 32; ++d) o[d] = 0.f;
      float m = -1e30f, l = 0.f;

      int jbeg, jcount, kbase;
      if (self) { jbeg = j * 32; jcount = 32; kbase = 0; }
      else      { jbeg = j * 16; jcount = 16; kbase = (n < 64) ? 64 : 0; }
      const int il = self ? n : (n & 63);
      const size_t mbase = (size_t)w64 * (NTOK * NTOK) + (size_t)il * NTOK;

      for (int jj = 0; jj < jcount; jj += 4) {
        const int jl = jbeg + jj;
        const int jg = kbase + jl;
        const float* kb = &k_s[kvrow(jg)];   // jg%16 in {0,4,8,12}: same skew
        float s[4];
        #pragma unroll
        for (int u = 0; u < 4; ++u) {
          const float* kr = kb + u * KVSTR;
          float t0 = 0.f, t1 = 0.f, t2 = 0.f, t3 = 0.f;
          #pragma unroll
          for (int kk = 0; kk < 8; ++kk) {
            float4 kv = *reinterpret_cast<const float4*>(kr + 4 * kk);
            t0 = fmaf(qfull[4 * kk],     kv.x, t0);
            t1 = fmaf(qfull[4 * kk + 1], kv.y, t1);
            t2 = fmaf(qfull[4 * kk + 2], kv.z, t2);
            t3 = fmaf(qfull[4 * kk + 3], kv.w, t3);
          }
          float sv = (t0 + t1) + (t2 + t3);
          sv += ld1<F32>(mask, mbase + (size_t)(jl + u));
          if (self) {
            const int jv = jl + u;
            const int dj = jv >> 6, hj = (jv >> 3) & 7, wj = jv & 7;
            const int idx = (bi_d - dj + 1) * 225 + (bi_h - hj + 7) * 15 + (bi_w - wj + 7);
            sv += ld1<F32>(rpb, (size_t)idx * 6 + h);
          }
          s[u] = sv;
        }
        float M = fmaxf(fmaxf(fmaxf(s[0], s[1]), fmaxf(s[2], s[3])), m);
        float corr = __expf(m - M);
        float p0 = __expf(s[0] - M), p1 = __expf(s[1] - M);
        float p2 = __expf(s[2] - M), p3 = __expf(s[3] - M);
        l = l * corr + ((p0 + p1) + (p2 + p3));
        const float* v0 = &v_s[kvrow(jg)];
        const float* v1 = v0 + KVSTR;
        const float* v2 = v1 + KVSTR;
        const float* v3 = v2 + KVSTR;
        #pragma unroll
        for (int kk = 0; kk < 8; ++kk) {
          float4 a0 = *reinterpret_cast<const float4*>(v0 + 4 * kk);
          float4 a1 = *reinterpret_cast<const float4*>(v1 + 4 * kk);
          float4 a2 = *reinterpret_cast<const float4*>(v2 + 4 * kk);
          float4 a3 = *reinterpret_cast<const float4*>(v3 + 4 * kk);
          o[4*kk]   = fmaf(o[4*kk],   corr, fmaf(p0, a0.x, fmaf(p1, a1.x, fmaf(p2, a2.x, p3 * a3.x))));
          o[4*kk+1] = fmaf(o[4*kk+1], corr, fmaf(p0, a0.y, fmaf(p1, a1.y, fmaf(p2, a2.y, p3 * a3.y))));
          o[4*kk+2] = fmaf(o[4*kk+2], corr, fmaf(p0, a0.z, fmaf(p1, a1.z, fmaf(p2, a2.z, p3 * a3.z))));
          o[4*kk+3] = fmaf(o[4*kk+3], corr, fmaf(p0, a0.w, fmaf(p1, a1.w, fmaf(p2, a2.w, p3 * a3.w))));
        }
        m = M;
      }
      // ---------- 4-lane butterfly merge; lane j==0 writes head-slab ----------
      {
        #pragma unroll
        for (int s2 = 1; s2 <= 2; s2 <<= 1) {
          float m2 = __shfl_xor(m, s2);
          float l2 = __shfl_xor(l, s2);
          float M  = fmaxf(m, m2);
          float e1 = __expf(m - M);
          float e2 = __expf(m2 - M);
          l = l * e1 + l2 * e2;
          #pragma unroll
          for (int d = 0; d < 30; ++d) {
            float o2v = __shfl_xor(o[d], s2);
            o[d] = o[d] * e1 + o2v * e2;
          }
          m = M;
        }
        if (j == 0) {
          const int r = self ? n : ((n + 64) & 127);   // mutual swaps halves
          float* srow = &slab[r * SLSTR];
          const float inv = 1.0f / l;
          #pragma unroll
          for (int d = 0; d < 30; ++d) srow[d] = o[d] * inv;
        }
      }
      __syncthreads();
      // ---------- projection accumulate: slab @ Wp[:, cb:cb+30) ----------
      {
        const int cb = self ? (CDIM + h * 30) : (h * 30);
        float s0[30];
        #pragma unroll
        for (int d = 0; d < 30; ++d) s0[d] = slab[rp * SLSTR + d];
        const size_t wrow = (size_t)(og * 45) * 360 + cb;
        #pragma unroll
        for (int o2 = 0; o2 < 45; ++o2) {
          const size_t wr = wrow + (size_t)o2 * 360;
          float t0 = 0.f;
          #pragma unroll
          for (int d = 0; d < 30; d += 2) {
            float2 w2 = ld2<F32>(Wp, wr + d);
            t0 = fmaf(s0[d], w2.x, fmaf(s0[d + 1], w2.y, t0));
          }
          acc[o2] += t0;
        }
      }
    } // heads
  } // passes

  // ---- epilogue: + b_proj, write FLOAT32 ----
  {
    float* o0 = out + ((size_t)b * NTOK + rp) * CDIM + og * 45;
    #pragma unroll
    for (int o2 = 0; o2 < 45; ++o2) {
      float bb = ld1<F32>(bp, og * 45 + o2);
      o0[o2] = acc[o2] + bb;
    }
  }
}

__global__ __launch_bounds__(512) void fused_all(
    const void* __restrict__ x,    const void* __restrict__ mask,
    const void* __restrict__ rpb,  const void* __restrict__ Wqs,
    const void* __restrict__ Wqm,  const void* __restrict__ Wp,
    const void* __restrict__ bp,   const int* __restrict__ flag,
    float* __restrict__ out)
{
  __shared__ __align__(16) float x_s[NTOK * XSTR];    // 93,184 B
  __shared__ __align__(16) float k_s[KVSZ];           // 18,560 B
  __shared__ __align__(16) float v_s[KVSZ];           // 18,560 B
  __shared__ __align__(16) float slab[NTOK * SLSTR];  // 16,896 B -> 147,200 B
  if (flag[0]) body<false>(x, mask, rpb, Wqs, Wqm, Wp, bp, out, x_s, k_s, v_s, slab);
  else         body<true >(x, mask, rpb, Wqs, Wqm, Wp, bp, out, x_s, k_s, v_s, slab);
}

// ---------------------------------------------------------------------------
extern "C" void kernel_launch(void* const* d_in, const int* in_sizes, int n_in,
                              void* d_out, int out_size, void* d_ws, size_t ws_size,
                              hipStream_t stream) {
  int* flag = (int*)d_ws;   // 4 bytes of ws -- the only scratch used
  detect_dtype<<<1, 256, 0, stream>>>((const u32*)d_in[0], flag);
  fused_all<<<1024, 512, 0, stream>>>(d_in[0], d_in[1], d_in[2], d_in[3],
                                      d_in[4], d_in[5], d_in[6], flag,
                                      (float*)d_out);
}

// Round 3
// 2460.607 us; speedup vs baseline: 4.4161x; 4.0581x over previous
//
#include <hip/hip_runtime.h>
#include <hip/hip_bf16.h>

// ============================================================================
// WindowAttention round 6: qkv GEMM re-tiling for operand reuse.
// r5 post-mortem: VGPR=112 was the allocator's choice (no big spills); the
// real stall is the qkv instruction stream: 1080 global dwordx4 per thread
// per head-pass with 4 fma/load and zero per-thread W reuse -> wave issues a
// VALU op every ~26 cyc (VALUBusy 15%) regardless of occupancy.
// Fix: thread tile = 4 tokens x 6 W-rows (nt=tid&31 -> tokens nt+32*i,
// ot=tid>>5 -> rows ot*6..+5; 30%6==0 so tiles never straddle q/k/v):
//   - 96 fma per (6 W + 4 x) loads (4x reuse);
//   - W loads: 2 distinct addresses per wave (32-lane broadcast), rr*720B
//     fits the 13-bit imm offset -> ~1 addr reg per c-step;
//   - W VMEM instrs/thread/head-pass: 1080 -> 270.
// q outputs now go to LDS (sq_s), time-sharing the slab buffer (disjoint
// lifetimes; extra barrier after q-load). Attention/merge/projection verbatim
// from the verified r5 body; all fma chains bit-identical -> same absmax.
// LDS: x_s 96,256 + k_s 18,560 + v_s 18,560 + sq_s 18,432 = 151,808 B.
// ============================================================================

typedef unsigned short u16;
typedef unsigned int   u32;

#define NTOK 128
#define CDIM 180
#define NHEAD 6
#define XSTR 188            // f32 x stride (mult of 4 for b128; 4*188%32=16)
#define KVSTR 36            // f32 k/v row stride (before skew)
#define KVSZ  4640
#define QSTR 36             // q rows in sq_s (mult of 4 for b128)
#define SLSTR 33            // slab view stride within sq_s (4224 <= 4608 fl)
#define QKSCALE 0.18257418583505536f   // 30^-0.5

__device__ __forceinline__ float bflo(u32 u){ return __uint_as_float(u << 16); }
__device__ __forceinline__ float bfhi(u32 u){ return __uint_as_float(u & 0xFFFF0000u); }
__device__ __forceinline__ float bf2f(u16 v){ return __uint_as_float(((u32)v) << 16); }

// skewed k/v row start: breaks same-bank aliasing of key-row streams
__device__ __forceinline__ int kvrow(int r){ return r * KVSTR + ((r >> 4) << 2); }

template<bool F32> __device__ __forceinline__ float ld1(const void* p, size_t i) {
  if constexpr (F32) return reinterpret_cast<const float*>(p)[i];
  else               return bf2f(reinterpret_cast<const u16*>(p)[i]);
}
template<bool F32> __device__ __forceinline__ float2 ld2(const void* p, size_t i) {
  if constexpr (F32) return *reinterpret_cast<const float2*>(reinterpret_cast<const float*>(p) + i);
  else {
    u32 r = *reinterpret_cast<const u32*>(reinterpret_cast<const u16*>(p) + i);
    return float2{bflo(r), bfhi(r)};
  }
}
template<bool F32> __device__ __forceinline__ float4 ld4(const void* p, size_t i) {
  if constexpr (F32) return *reinterpret_cast<const float4*>(reinterpret_cast<const float*>(p) + i);
  else {
    uint2 r = *reinterpret_cast<const uint2*>(reinterpret_cast<const u16*>(p) + i);
    return float4{bflo(r.x), bfhi(r.x), bflo(r.y), bfhi(r.y)};
  }
}

// ---------------------------------------------------------------------------
// dtype detector (unchanged): flag=1 => bf16 inputs.
// ---------------------------------------------------------------------------
__global__ void detect_dtype(const u32* __restrict__ xw, int* __restrict__ flag) {
  __shared__ int cnt[256];
  int c = 0;
  for (int i = threadIdx.x; i < 4096; i += 256) {
    u32 e = (xw[i] >> 7) & 0xFF;
    c += (e >= 0x58 && e <= 0x90) ? 1 : 0;
  }
  cnt[threadIdx.x] = c;
  __syncthreads();
  if (threadIdx.x == 0) {
    int t = 0;
    for (int i = 0; i < 256; ++i) t += cnt[i];
    flag[0] = (t >= 2458) ? 1 : 0;
  }
}

// ---------------------------------------------------------------------------
// fused per-window body, 512 threads
// ---------------------------------------------------------------------------
template<bool F32>
__device__ void body(const void* __restrict__ x,    // (1024,128,180)
                     const void* __restrict__ mask, // (64,128,128)
                     const void* __restrict__ rpb,  // (675,6)
                     const void* __restrict__ Wqs,  // (540,180)
                     const void* __restrict__ Wqm,  // (540,180)
                     const void* __restrict__ Wp,   // (180,360)
                     const void* __restrict__ bp,   // (180)
                     float* __restrict__ out,       // (1024,128,180) f32
                     float* x_s, float* k_s, float* v_s, float* sq_s)
{
  const int tid = threadIdx.x;
  const int b   = blockIdx.x;
  const int n   = tid >> 2;        // attention: token (query)
  const int j   = tid & 3;         // attention: quarter lane
  const int w64 = b & 63;

  // qkv GEMM mapping: 4 tokens x 6 W-rows per thread
  const int nt  = tid & 31;        // token base: tokens {nt+32*i}
  const int ot  = tid >> 5;        // row-tile 0..15 (15 idle)
  const bool act = (ot < 15);
  const int grp = ot / 5;          // 0=q, 1=k, 2=v  (3 for the idle tile)
  const int lr0 = (ot - grp * 5) * 6;   // local row 0..24 within the 30

  // projection ownership: 1 token x 45 out-cols
  const int rp = tid & 127;
  const int og = __builtin_amdgcn_readfirstlane(tid >> 7);
  float acc[45];
  #pragma unroll
  for (int o2 = 0; o2 < 45; ++o2) acc[o2] = 0.f;

  // bias i-coords for self attention (query n)
  const int bi_d = n >> 6, bi_h = (n >> 3) & 7, bi_w = n & 7;

  // ---- stage x window into LDS (f32, exact) ----
  {
    const size_t xbase = (size_t)b * (NTOK * CDIM);
    for (int i = tid * 4; i < NTOK * CDIM; i += 2048) {
      float4 f = ld4<F32>(x, xbase + i);
      int r = i / CDIM, c = i - r * CDIM;     // c stays multiple of 4
      float* dst = &x_s[r * XSTR + c];
      dst[0] = f.x; dst[1] = f.y; dst[2] = f.z; dst[3] = f.w;
    }
  }
  // ---- one-time zero of k/v pad cols 30,31 (q pad handled at load) ----
  if (tid < NTOK) {
    const int kb = kvrow(tid);
    k_s[kb + 30] = 0.f; k_s[kb + 31] = 0.f;
    v_s[kb + 30] = 0.f; v_s[kb + 31] = 0.f;
  }

  for (int pass = 0; pass < 2; ++pass) {
    const bool self = (pass == 0);
    const void* W = self ? Wqs : Wqm;
    if (!self) {
      __syncthreads();
      // x += sine position encoding, computed on the fly (f32, no rounding)
      for (int i = tid; i < NTOK * CDIM; i += 512) {
        int r = i / CDIM, c = i - r * CDIM;
        int n64 = r & 63;
        int t = (c < 90) ? c : (c - 90);
        float e = (c < 90) ? (float)((n64 >> 3) + 1) : (float)((n64 & 7) + 1);
        float embed = e * 0.78539807f;                 // 2*pi / 8.000001
        float expo  = (float)(t & ~1) * (1.0f / 90.0f);
        float arg   = embed * exp2f(-13.2877124f * expo);  // 10000^-expo
        float pbv   = (t & 1) ? cosf(arg) : sinf(arg);
        x_s[r * XSTR + c] += pbv;
      }
    }
    for (int h = 0; h < NHEAD; ++h) {
      __syncthreads();
      // ---------- qkv mini-GEMM: 4 tokens x 6 rows, K=180 ----------
      if (act) {
        float a[4][6];
        #pragma unroll
        for (int i = 0; i < 4; ++i)
          #pragma unroll
          for (int rr = 0; rr < 6; ++rr) a[i][rr] = 0.f;
        const size_t wb = (size_t)(grp * 180 + h * 30 + lr0) * CDIM;
        const float* xr = &x_s[nt * XSTR];
        #pragma unroll 3
        for (int c = 0; c < CDIM; c += 4) {
          float4 wv[6];
          #pragma unroll
          for (int rr = 0; rr < 6; ++rr)
            wv[rr] = ld4<F32>(W, wb + (size_t)rr * CDIM + c);
          #pragma unroll
          for (int i = 0; i < 4; ++i) {
            float4 xv = *reinterpret_cast<const float4*>(xr + i * (32 * XSTR) + c);
            #pragma unroll
            for (int rr = 0; rr < 6; ++rr)
              a[i][rr] = fmaf(xv.x, wv[rr].x,
                         fmaf(xv.y, wv[rr].y,
                         fmaf(xv.z, wv[rr].z,
                         fmaf(xv.w, wv[rr].w, a[i][rr]))));
          }
        }
        // write q (scaled) / k / v to LDS
        #pragma unroll
        for (int i = 0; i < 4; ++i) {
          const int n2 = 32 * i + nt;
          #pragma unroll
          for (int rr = 0; rr < 6; ++rr) {
            const int lr = lr0 + rr;
            const float val = a[i][rr];
            if (grp == 0)      sq_s[n2 * QSTR + lr] = val * QKSCALE;
            else if (grp == 1) k_s[kvrow(n2) + lr] = val;
            else               v_s[kvrow(n2) + lr] = val;
          }
        }
      }
      __syncthreads();
      // ---------- load this thread's q row from LDS ----------
      float qfull[32];
      {
        const float* qr = &sq_s[n * QSTR];
        #pragma unroll
        for (int kk = 0; kk < 7; ++kk) {
          float4 t4 = *reinterpret_cast<const float4*>(qr + 4 * kk);
          qfull[4*kk]   = t4.x; qfull[4*kk+1] = t4.y;
          qfull[4*kk+2] = t4.z; qfull[4*kk+3] = t4.w;
        }
        float2 t2 = *reinterpret_cast<const float2*>(qr + 28);
        qfull[28] = t2.x; qfull[29] = t2.y;
        qfull[30] = 0.f;  qfull[31] = 0.f;
      }
      // q reads must finish before anyone overwrites sq_s as slab
      __syncthreads();
      // ---------- attention: query n, key-range split 4 ways by j ----------
      float o[32];
      #pragma unroll
      for (int d = 0; d < 32; ++d) o[d] = 0.f;
      float m = -1e30f, l = 0.f;

      int jbeg, jcount, kbase;
      if (self) { jbeg = j * 32; jcount = 32; kbase = 0; }
      else      { jbeg = j * 16; jcount = 16; kbase = (n < 64) ? 64 : 0; }
      const int il = self ? n : (n & 63);
      const size_t mbase = (size_t)w64 * (NTOK * NTOK) + (size_t)il * NTOK;

      for (int jj = 0; jj < jcount; jj += 4) {
        const int jl = jbeg + jj;
        const int jg = kbase + jl;
        const float* kb = &k_s[kvrow(jg)];   // jg%16 in {0,4,8,12}: same skew
        float s[4];
        #pragma unroll
        for (int u = 0; u < 4; ++u) {
          const float* kr = kb + u * KVSTR;
          float t0 = 0.f, t1 = 0.f, t2 = 0.f, t3 = 0.f;
          #pragma unroll
          for (int kk = 0; kk < 8; ++kk) {
            float4 kv = *reinterpret_cast<const float4*>(kr + 4 * kk);
            t0 = fmaf(qfull[4 * kk],     kv.x, t0);
            t1 = fmaf(qfull[4 * kk + 1], kv.y, t1);
            t2 = fmaf(qfull[4 * kk + 2], kv.z, t2);
            t3 = fmaf(qfull[4 * kk + 3], kv.w, t3);
          }
          float sv = (t0 + t1) + (t2 + t3);
          sv += ld1<F32>(mask, mbase + (size_t)(jl + u));
          if (self) {
            const int jv = jl + u;
            const int dj = jv >> 6, hj = (jv >> 3) & 7, wj = jv & 7;
            const int idx = (bi_d - dj + 1) * 225 + (bi_h - hj + 7) * 15 + (bi_w - wj + 7);
            sv += ld1<F32>(rpb, (size_t)idx * 6 + h);
          }
          s[u] = sv;
        }
        float M = fmaxf(fmaxf(fmaxf(s[0], s[1]), fmaxf(s[2], s[3])), m);
        float corr = __expf(m - M);
        float p0 = __expf(s[0] - M), p1 = __expf(s[1] - M);
        float p2 = __expf(s[2] - M), p3 = __expf(s[3] - M);
        l = l * corr + ((p0 + p1) + (p2 + p3));
        const float* v0 = &v_s[kvrow(jg)];
        const float* v1 = v0 + KVSTR;
        const float* v2 = v1 + KVSTR;
        const float* v3 = v2 + KVSTR;
        #pragma unroll
        for (int kk = 0; kk < 8; ++kk) {
          float4 a0 = *reinterpret_cast<const float4*>(v0 + 4 * kk);
          float4 a1 = *reinterpret_cast<const float4*>(v1 + 4 * kk);
          float4 a2 = *reinterpret_cast<const float4*>(v2 + 4 * kk);
          float4 a3 = *reinterpret_cast<const float4*>(v3 + 4 * kk);
          o[4*kk]   = fmaf(o[4*kk],   corr, fmaf(p0, a0.x, fmaf(p1, a1.x, fmaf(p2, a2.x, p3 * a3.x))));
          o[4*kk+1] = fmaf(o[4*kk+1], corr, fmaf(p0, a0.y, fmaf(p1, a1.y, fmaf(p2, a2.y, p3 * a3.y))));
          o[4*kk+2] = fmaf(o[4*kk+2], corr, fmaf(p0, a0.z, fmaf(p1, a1.z, fmaf(p2, a2.z, p3 * a3.z))));
          o[4*kk+3] = fmaf(o[4*kk+3], corr, fmaf(p0, a0.w, fmaf(p1, a1.w, fmaf(p2, a2.w, p3 * a3.w))));
        }
        m = M;
      }
      // ---------- 4-lane butterfly merge; lane j==0 writes head-slab ----------
      {
        #pragma unroll
        for (int s2 = 1; s2 <= 2; s2 <<= 1) {
          float m2 = __shfl_xor(m, s2);
          float l2 = __shfl_xor(l, s2);
          float M  = fmaxf(m, m2);
          float e1 = __expf(m - M);
          float e2 = __expf(m2 - M);
          l = l * e1 + l2 * e2;
          #pragma unroll
          for (int d = 0; d < 30; ++d) {
            float o2v = __shfl_xor(o[d], s2);
            o[d] = o[d] * e1 + o2v * e2;
          }
          m = M;
        }
        if (j == 0) {
          const int r = self ? n : ((n + 64) & 127);   // mutual swaps halves
          float* srow = &sq_s[r * SLSTR];              // slab view
          const float inv = 1.0f / l;
          #pragma unroll
          for (int d = 0; d < 30; ++d) srow[d] = o[d] * inv;
        }
      }
      __syncthreads();
      // ---------- projection accumulate: slab @ Wp[:, cb:cb+30) ----------
      {
        const int cb = self ? (CDIM + h * 30) : (h * 30);
        float s0[30];
        #pragma unroll
        for (int d = 0; d < 30; ++d) s0[d] = sq_s[rp * SLSTR + d];
        const size_t wrow = (size_t)(og * 45) * 360 + cb;
        #pragma unroll
        for (int o2 = 0; o2 < 45; ++o2) {
          const size_t wr = wrow + (size_t)o2 * 360;
          float t0 = 0.f;
          #pragma unroll
          for (int d = 0; d < 30; d += 2) {
            float2 w2 = ld2<F32>(Wp, wr + d);
            t0 = fmaf(s0[d], w2.x, fmaf(s0[d + 1], w2.y, t0));
          }
          acc[o2] += t0;
        }
      }
    } // heads
  } // passes

  // ---- epilogue: + b_proj, write FLOAT32 ----
  {
    float* o0 = out + ((size_t)b * NTOK + rp) * CDIM + og * 45;
    #pragma unroll
    for (int o2 = 0; o2 < 45; ++o2) {
      float bb = ld1<F32>(bp, og * 45 + o2);
      o0[o2] = acc[o2] + bb;
    }
  }
}

__global__ __launch_bounds__(512) void fused_all(
    const void* __restrict__ x,    const void* __restrict__ mask,
    const void* __restrict__ rpb,  const void* __restrict__ Wqs,
    const void* __restrict__ Wqm,  const void* __restrict__ Wp,
    const void* __restrict__ bp,   const int* __restrict__ flag,
    float* __restrict__ out)
{
  __shared__ __align__(16) float x_s[NTOK * XSTR];    // 96,256 B
  __shared__ __align__(16) float k_s[KVSZ];           // 18,560 B
  __shared__ __align__(16) float v_s[KVSZ];           // 18,560 B
  __shared__ __align__(16) float sq_s[NTOK * QSTR];   // 18,432 B -> 151,808 B
  if (flag[0]) body<false>(x, mask, rpb, Wqs, Wqm, Wp, bp, out, x_s, k_s, v_s, sq_s);
  else         body<true >(x, mask, rpb, Wqs, Wqm, Wp, bp, out, x_s, k_s, v_s, sq_s);
}

// ---------------------------------------------------------------------------
extern "C" void kernel_launch(void* const* d_in, const int* in_sizes, int n_in,
                              void* d_out, int out_size, void* d_ws, size_t ws_size,
                              hipStream_t stream) {
  int* flag = (int*)d_ws;   // 4 bytes of ws -- the only scratch used
  detect_dtype<<<1, 256, 0, stream>>>((const u32*)d_in[0], flag);
  fused_all<<<1024, 512, 0, stream>>>(d_in[0], d_in[1], d_in[2], d_in[3],
                                      d_in[4], d_in[5], d_in[6], flag,
                                      (float*)d_out);
}

// Round 4
// 2410.838 us; speedup vs baseline: 4.5073x; 1.0206x over previous
//
#include <hip/hip_runtime.h>
#include <hip/hip_bf16.h>

// ============================================================================
// WindowAttention round 7: attention re-tiling — 2 queries/thread, 8-way keys.
// r6 post-mortem: prediction matched (9985->2461 us, VALUBusy 45.7%). Now
// co-bound: VALU-busy 1124 us vs pure-math floor 550 us, and attention LDS
// traffic (each query reads all 128 keys x 32 fl x {K,V} = 4KB -> 4MB/block/
// self-head) puts the DS pipe at ~40% busy, serialized with VALU via the
// ds_read->fma dependency.
// Fix: thread = (g=tid>>3 -> queries {2g,2g+1}, j8=tid&7 -> key slice).
// Every K/V float4 read feeds BOTH queries -> attention LDS traffic halves
// (pairs sit in the same half, so mutual shares the key range too). Merge is
// now a 3-level 8-lane butterfly (same formula as the verified 2-level one).
// K/V wave read pattern becomes 8 rows spaced 16 apart = conflict-free under
// the kvrow skew (580a mod 32 distinct). qkv GEMM / projection / epilogue
// verbatim from r6. ~215 VGPR live; plan B if spills: re-read q from LDS.
// LDS unchanged: 151,808 B.
// ============================================================================

typedef unsigned short u16;
typedef unsigned int   u32;

#define NTOK 128
#define CDIM 180
#define NHEAD 6
#define XSTR 188            // f32 x stride
#define KVSTR 36            // f32 k/v row stride (before skew)
#define KVSZ  4640
#define QSTR 36             // q rows in sq_s
#define SLSTR 33            // slab view stride within sq_s
#define QKSCALE 0.18257418583505536f   // 30^-0.5

__device__ __forceinline__ float bflo(u32 u){ return __uint_as_float(u << 16); }
__device__ __forceinline__ float bfhi(u32 u){ return __uint_as_float(u & 0xFFFF0000u); }
__device__ __forceinline__ float bf2f(u16 v){ return __uint_as_float(((u32)v) << 16); }

// skewed k/v row start: rows spaced 16 apart land on distinct bank quads
__device__ __forceinline__ int kvrow(int r){ return r * KVSTR + ((r >> 4) << 2); }

template<bool F32> __device__ __forceinline__ float ld1(const void* p, size_t i) {
  if constexpr (F32) return reinterpret_cast<const float*>(p)[i];
  else               return bf2f(reinterpret_cast<const u16*>(p)[i]);
}
template<bool F32> __device__ __forceinline__ float2 ld2(const void* p, size_t i) {
  if constexpr (F32) return *reinterpret_cast<const float2*>(reinterpret_cast<const float*>(p) + i);
  else {
    u32 r = *reinterpret_cast<const u32*>(reinterpret_cast<const u16*>(p) + i);
    return float2{bflo(r), bfhi(r)};
  }
}
template<bool F32> __device__ __forceinline__ float4 ld4(const void* p, size_t i) {
  if constexpr (F32) return *reinterpret_cast<const float4*>(reinterpret_cast<const float*>(p) + i);
  else {
    uint2 r = *reinterpret_cast<const uint2*>(reinterpret_cast<const u16*>(p) + i);
    return float4{bflo(r.x), bfhi(r.x), bflo(r.y), bfhi(r.y)};
  }
}

// ---------------------------------------------------------------------------
// dtype detector (unchanged): flag=1 => bf16 inputs.
// ---------------------------------------------------------------------------
__global__ void detect_dtype(const u32* __restrict__ xw, int* __restrict__ flag) {
  __shared__ int cnt[256];
  int c = 0;
  for (int i = threadIdx.x; i < 4096; i += 256) {
    u32 e = (xw[i] >> 7) & 0xFF;
    c += (e >= 0x58 && e <= 0x90) ? 1 : 0;
  }
  cnt[threadIdx.x] = c;
  __syncthreads();
  if (threadIdx.x == 0) {
    int t = 0;
    for (int i = 0; i < 256; ++i) t += cnt[i];
    flag[0] = (t >= 2458) ? 1 : 0;
  }
}

// ---------------------------------------------------------------------------
// fused per-window body, 512 threads
// ---------------------------------------------------------------------------
template<bool F32>
__device__ void body(const void* __restrict__ x,    // (1024,128,180)
                     const void* __restrict__ mask, // (64,128,128)
                     const void* __restrict__ rpb,  // (675,6)
                     const void* __restrict__ Wqs,  // (540,180)
                     const void* __restrict__ Wqm,  // (540,180)
                     const void* __restrict__ Wp,   // (180,360)
                     const void* __restrict__ bp,   // (180)
                     float* __restrict__ out,       // (1024,128,180) f32
                     float* x_s, float* k_s, float* v_s, float* sq_s)
{
  const int tid = threadIdx.x;
  const int b   = blockIdx.x;
  const int w64 = b & 63;

  // attention mapping: query pair {2g, 2g+1}, key slice j8 of 8
  const int g  = tid >> 3;
  const int j8 = tid & 7;
  const int n0 = g * 2, n1 = n0 + 1;

  // qkv GEMM mapping: 4 tokens x 6 W-rows per thread (unchanged from r6)
  const int nt  = tid & 31;
  const int ot  = tid >> 5;
  const bool act = (ot < 15);
  const int grp = ot / 5;
  const int lr0 = (ot - grp * 5) * 6;

  // projection ownership: 1 token x 45 out-cols
  const int rp = tid & 127;
  const int og = __builtin_amdgcn_readfirstlane(tid >> 7);
  float acc[45];
  #pragma unroll
  for (int o2 = 0; o2 < 45; ++o2) acc[o2] = 0.f;

  // self-attention bias i-coords for both queries
  const int b0d = n0 >> 6, b0h = (n0 >> 3) & 7, b0w = n0 & 7;
  const int b1d = n1 >> 6, b1h = (n1 >> 3) & 7, b1w = n1 & 7;

  // ---- stage x window into LDS (f32, exact) ----
  {
    const size_t xbase = (size_t)b * (NTOK * CDIM);
    for (int i = tid * 4; i < NTOK * CDIM; i += 2048) {
      float4 f = ld4<F32>(x, xbase + i);
      int r = i / CDIM, c = i - r * CDIM;
      float* dst = &x_s[r * XSTR + c];
      dst[0] = f.x; dst[1] = f.y; dst[2] = f.z; dst[3] = f.w;
    }
  }
  // ---- one-time zero of k/v pad cols 30,31 ----
  if (tid < NTOK) {
    const int kb = kvrow(tid);
    k_s[kb + 30] = 0.f; k_s[kb + 31] = 0.f;
    v_s[kb + 30] = 0.f; v_s[kb + 31] = 0.f;
  }

  for (int pass = 0; pass < 2; ++pass) {
    const bool self = (pass == 0);
    const void* W = self ? Wqs : Wqm;
    if (!self) {
      __syncthreads();
      // x += sine position encoding, computed on the fly (f32, no rounding)
      for (int i = tid; i < NTOK * CDIM; i += 512) {
        int r = i / CDIM, c = i - r * CDIM;
        int n64 = r & 63;
        int t = (c < 90) ? c : (c - 90);
        float e = (c < 90) ? (float)((n64 >> 3) + 1) : (float)((n64 & 7) + 1);
        float embed = e * 0.78539807f;                 // 2*pi / 8.000001
        float expo  = (float)(t & ~1) * (1.0f / 90.0f);
        float arg   = embed * exp2f(-13.2877124f * expo);  // 10000^-expo
        float pbv   = (t & 1) ? cosf(arg) : sinf(arg);
        x_s[r * XSTR + c] += pbv;
      }
    }
    for (int h = 0; h < NHEAD; ++h) {
      __syncthreads();
      // ---------- qkv mini-GEMM: 4 tokens x 6 rows, K=180 (verbatim r6) ----
      if (act) {
        float a[4][6];
        #pragma unroll
        for (int i = 0; i < 4; ++i)
          #pragma unroll
          for (int rr = 0; rr < 6; ++rr) a[i][rr] = 0.f;
        const size_t wb = (size_t)(grp * 180 + h * 30 + lr0) * CDIM;
        const float* xr = &x_s[nt * XSTR];
        #pragma unroll 3
        for (int c = 0; c < CDIM; c += 4) {
          float4 wv[6];
          #pragma unroll
          for (int rr = 0; rr < 6; ++rr)
            wv[rr] = ld4<F32>(W, wb + (size_t)rr * CDIM + c);
          #pragma unroll
          for (int i = 0; i < 4; ++i) {
            float4 xv = *reinterpret_cast<const float4*>(xr + i * (32 * XSTR) + c);
            #pragma unroll
            for (int rr = 0; rr < 6; ++rr)
              a[i][rr] = fmaf(xv.x, wv[rr].x,
                         fmaf(xv.y, wv[rr].y,
                         fmaf(xv.z, wv[rr].z,
                         fmaf(xv.w, wv[rr].w, a[i][rr]))));
          }
        }
        #pragma unroll
        for (int i = 0; i < 4; ++i) {
          const int n2 = 32 * i + nt;
          #pragma unroll
          for (int rr = 0; rr < 6; ++rr) {
            const int lr = lr0 + rr;
            const float val = a[i][rr];
            if (grp == 0)      sq_s[n2 * QSTR + lr] = val * QKSCALE;
            else if (grp == 1) k_s[kvrow(n2) + lr] = val;
            else               v_s[kvrow(n2) + lr] = val;
          }
        }
      }
      __syncthreads();
      // ---------- load both q rows from LDS ----------
      float qf0[32], qf1[32];
      {
        const float* qr0 = &sq_s[n0 * QSTR];
        const float* qr1 = &sq_s[n1 * QSTR];
        #pragma unroll
        for (int kk = 0; kk < 7; ++kk) {
          float4 t4 = *reinterpret_cast<const float4*>(qr0 + 4 * kk);
          qf0[4*kk] = t4.x; qf0[4*kk+1] = t4.y; qf0[4*kk+2] = t4.z; qf0[4*kk+3] = t4.w;
          float4 u4 = *reinterpret_cast<const float4*>(qr1 + 4 * kk);
          qf1[4*kk] = u4.x; qf1[4*kk+1] = u4.y; qf1[4*kk+2] = u4.z; qf1[4*kk+3] = u4.w;
        }
        float2 t2 = *reinterpret_cast<const float2*>(qr0 + 28);
        qf0[28] = t2.x; qf0[29] = t2.y; qf0[30] = 0.f; qf0[31] = 0.f;
        float2 u2 = *reinterpret_cast<const float2*>(qr1 + 28);
        qf1[28] = u2.x; qf1[29] = u2.y; qf1[30] = 0.f; qf1[31] = 0.f;
      }
      // q reads must finish before anyone overwrites sq_s as slab
      __syncthreads();
      // ---------- attention: queries n0,n1; key slice j8 of 8 ----------
      float o0[32], o1[32];
      #pragma unroll
      for (int d = 0; d < 32; ++d) { o0[d] = 0.f; o1[d] = 0.f; }
      float m0 = -1e30f, l0 = 0.f, m1 = -1e30f, l1 = 0.f;

      int jbeg, jcount, kbase;
      if (self) { jbeg = j8 * 16; jcount = 16; kbase = 0; }
      else      { jbeg = j8 * 8;  jcount = 8;  kbase = (n0 < 64) ? 64 : 0; }
      const int il0 = self ? n0 : (n0 & 63);
      const size_t mbase0 = (size_t)w64 * (NTOK * NTOK) + (size_t)il0 * NTOK;
      const size_t mbase1 = mbase0 + NTOK;   // il1 = il0+1 in both passes

      for (int jj = 0; jj < jcount; jj += 4) {
        const int jl = jbeg + jj;
        const int jg = kbase + jl;
        const float* kb = &k_s[kvrow(jg)];   // jg%16 in {0,4,8,12}: same skew
        float s0[4], s1[4];
        #pragma unroll
        for (int u = 0; u < 4; ++u) {
          const float* kr = kb + u * KVSTR;
          float a0 = 0.f, a1 = 0.f, a2 = 0.f, a3 = 0.f;
          float c0 = 0.f, c1 = 0.f, c2 = 0.f, c3 = 0.f;
          #pragma unroll
          for (int kk = 0; kk < 8; ++kk) {
            float4 kv = *reinterpret_cast<const float4*>(kr + 4 * kk);
            a0 = fmaf(qf0[4*kk],   kv.x, a0);
            a1 = fmaf(qf0[4*kk+1], kv.y, a1);
            a2 = fmaf(qf0[4*kk+2], kv.z, a2);
            a3 = fmaf(qf0[4*kk+3], kv.w, a3);
            c0 = fmaf(qf1[4*kk],   kv.x, c0);
            c1 = fmaf(qf1[4*kk+1], kv.y, c1);
            c2 = fmaf(qf1[4*kk+2], kv.z, c2);
            c3 = fmaf(qf1[4*kk+3], kv.w, c3);
          }
          float sv0 = (a0 + a1) + (a2 + a3);
          float sv1 = (c0 + c1) + (c2 + c3);
          sv0 += ld1<F32>(mask, mbase0 + (size_t)(jl + u));
          sv1 += ld1<F32>(mask, mbase1 + (size_t)(jl + u));
          if (self) {
            const int jv = jl + u;
            const int dj = jv >> 6, hj = (jv >> 3) & 7, wj = jv & 7;
            const int i0 = (b0d - dj + 1) * 225 + (b0h - hj + 7) * 15 + (b0w - wj + 7);
            const int i1 = (b1d - dj + 1) * 225 + (b1h - hj + 7) * 15 + (b1w - wj + 7);
            sv0 += ld1<F32>(rpb, (size_t)i0 * 6 + h);
            sv1 += ld1<F32>(rpb, (size_t)i1 * 6 + h);
          }
          s0[u] = sv0; s1[u] = sv1;
        }
        // online softmax, both states
        float M0 = fmaxf(fmaxf(fmaxf(s0[0], s0[1]), fmaxf(s0[2], s0[3])), m0);
        float M1 = fmaxf(fmaxf(fmaxf(s1[0], s1[1]), fmaxf(s1[2], s1[3])), m1);
        float cr0 = __expf(m0 - M0), cr1 = __expf(m1 - M1);
        float p00 = __expf(s0[0] - M0), p01 = __expf(s0[1] - M0);
        float p02 = __expf(s0[2] - M0), p03 = __expf(s0[3] - M0);
        float p10 = __expf(s1[0] - M1), p11 = __expf(s1[1] - M1);
        float p12 = __expf(s1[2] - M1), p13 = __expf(s1[3] - M1);
        l0 = l0 * cr0 + ((p00 + p01) + (p02 + p03));
        l1 = l1 * cr1 + ((p10 + p11) + (p12 + p13));
        const float* v0 = &v_s[kvrow(jg)];
        const float* v1 = v0 + KVSTR;
        const float* v2 = v1 + KVSTR;
        const float* v3 = v2 + KVSTR;
        #pragma unroll
        for (int kk = 0; kk < 8; ++kk) {
          float4 a0 = *reinterpret_cast<const float4*>(v0 + 4 * kk);
          float4 a1 = *reinterpret_cast<const float4*>(v1 + 4 * kk);
          float4 a2 = *reinterpret_cast<const float4*>(v2 + 4 * kk);
          float4 a3 = *reinterpret_cast<const float4*>(v3 + 4 * kk);
          o0[4*kk]   = fmaf(o0[4*kk],   cr0, fmaf(p00, a0.x, fmaf(p01, a1.x, fmaf(p02, a2.x, p03 * a3.x))));
          o0[4*kk+1] = fmaf(o0[4*kk+1], cr0, fmaf(p00, a0.y, fmaf(p01, a1.y, fmaf(p02, a2.y, p03 * a3.y))));
          o0[4*kk+2] = fmaf(o0[4*kk+2], cr0, fmaf(p00, a0.z, fmaf(p01, a1.z, fmaf(p02, a2.z, p03 * a3.z))));
          o0[4*kk+3] = fmaf(o0[4*kk+3], cr0, fmaf(p00, a0.w, fmaf(p01, a1.w, fmaf(p02, a2.w, p03 * a3.w))));
          o1[4*kk]   = fmaf(o1[4*kk],   cr1, fmaf(p10, a0.x, fmaf(p11, a1.x, fmaf(p12, a2.x, p13 * a3.x))));
          o1[4*kk+1] = fmaf(o1[4*kk+1], cr1, fmaf(p10, a0.y, fmaf(p11, a1.y, fmaf(p12, a2.y, p13 * a3.y))));
          o1[4*kk+2] = fmaf(o1[4*kk+2], cr1, fmaf(p10, a0.z, fmaf(p11, a1.z, fmaf(p12, a2.z, p13 * a3.z))));
          o1[4*kk+3] = fmaf(o1[4*kk+3], cr1, fmaf(p10, a0.w, fmaf(p11, a1.w, fmaf(p12, a2.w, p13 * a3.w))));
        }
        m0 = M0; m1 = M1;
      }
      // ---------- 3-level 8-lane butterfly merge ----------
      {
        #pragma unroll
        for (int s2 = 1; s2 <= 4; s2 <<= 1) {
          float mm = __shfl_xor(m0, s2);
          float ll = __shfl_xor(l0, s2);
          float M  = fmaxf(m0, mm);
          float e1 = __expf(m0 - M);
          float e2 = __expf(mm - M);
          l0 = l0 * e1 + ll * e2;
          #pragma unroll
          for (int d = 0; d < 30; ++d) {
            float ov = __shfl_xor(o0[d], s2);
            o0[d] = o0[d] * e1 + ov * e2;
          }
          m0 = M;
          float mn = __shfl_xor(m1, s2);
          float ln = __shfl_xor(l1, s2);
          float N  = fmaxf(m1, mn);
          float f1 = __expf(m1 - N);
          float f2 = __expf(mn - N);
          l1 = l1 * f1 + ln * f2;
          #pragma unroll
          for (int d = 0; d < 30; ++d) {
            float ov = __shfl_xor(o1[d], s2);
            o1[d] = o1[d] * f1 + ov * f2;
          }
          m1 = N;
        }
        if (j8 == 0) {
          const int r = self ? n0 : ((n0 + 64) & 127);
          float* srow = &sq_s[r * SLSTR];
          const float inv = 1.0f / l0;
          #pragma unroll
          for (int d = 0; d < 30; ++d) srow[d] = o0[d] * inv;
        } else if (j8 == 4) {
          const int r = self ? n1 : ((n1 + 64) & 127);
          float* srow = &sq_s[r * SLSTR];
          const float inv = 1.0f / l1;
          #pragma unroll
          for (int d = 0; d < 30; ++d) srow[d] = o1[d] * inv;
        }
      }
      __syncthreads();
      // ---------- projection accumulate: slab @ Wp[:, cb:cb+30) ----------
      {
        const int cb = self ? (CDIM + h * 30) : (h * 30);
        float s0p[30];
        #pragma unroll
        for (int d = 0; d < 30; ++d) s0p[d] = sq_s[rp * SLSTR + d];
        const size_t wrow = (size_t)(og * 45) * 360 + cb;
        #pragma unroll
        for (int o2 = 0; o2 < 45; ++o2) {
          const size_t wr = wrow + (size_t)o2 * 360;
          float t0 = 0.f;
          #pragma unroll
          for (int d = 0; d < 30; d += 2) {
            float2 w2 = ld2<F32>(Wp, wr + d);
            t0 = fmaf(s0p[d], w2.x, fmaf(s0p[d + 1], w2.y, t0));
          }
          acc[o2] += t0;
        }
      }
    } // heads
  } // passes

  // ---- epilogue: + b_proj, write FLOAT32 ----
  {
    float* o0 = out + ((size_t)b * NTOK + rp) * CDIM + og * 45;
    #pragma unroll
    for (int o2 = 0; o2 < 45; ++o2) {
      float bb = ld1<F32>(bp, og * 45 + o2);
      o0[o2] = acc[o2] + bb;
    }
  }
}

__global__ __launch_bounds__(512) void fused_all(
    const void* __restrict__ x,    const void* __restrict__ mask,
    const void* __restrict__ rpb,  const void* __restrict__ Wqs,
    const void* __restrict__ Wqm,  const void* __restrict__ Wp,
    const void* __restrict__ bp,   const int* __restrict__ flag,
    float* __restrict__ out)
{
  __shared__ __align__(16) float x_s[NTOK * XSTR];    // 96,256 B
  __shared__ __align__(16) float k_s[KVSZ];           // 18,560 B
  __shared__ __align__(16) float v_s[KVSZ];           // 18,560 B
  __shared__ __align__(16) float sq_s[NTOK * QSTR];   // 18,432 B -> 151,808 B
  if (flag[0]) body<false>(x, mask, rpb, Wqs, Wqm, Wp, bp, out, x_s, k_s, v_s, sq_s);
  else         body<true >(x, mask, rpb, Wqs, Wqm, Wp, bp, out, x_s, k_s, v_s, sq_s);
}

// ---------------------------------------------------------------------------
extern "C" void kernel_launch(void* const* d_in, const int* in_sizes, int n_in,
                              void* d_out, int out_size, void* d_ws, size_t ws_size,
                              hipStream_t stream) {
  int* flag = (int*)d_ws;   // 4 bytes of ws -- the only scratch used
  detect_dtype<<<1, 256, 0, stream>>>((const u32*)d_in[0], flag);
  fused_all<<<1024, 512, 0, stream>>>(d_in[0], d_in[1], d_in[2], d_in[3],
                                      d_in[4], d_in[5], d_in[6], flag,
                                      (float*)d_out);
}